// Round 15
// baseline (389.642 us; speedup 1.0000x reference)
//
#include <hip/hip_runtime.h>
#include <stdint.h>

// Problem constants (fixed by reference setup_inputs)
constexpr int N = 65536, K = 512, F = 512;
constexpr float ASCALE = 127.0f / 3.0f;   // activation scale (fixed bound 3.0)

typedef int  int4v  __attribute__((ext_vector_type(4)));   // 4 dwords = 16 int8 / i32x4 acc

// round-half-even then clip to [-127,127] (reference order: round, then clip)
__device__ __forceinline__ int quant_i(float v, float s) {
    float q = rintf(v * s);
    q = fminf(fmaxf(q, -127.0f), 127.0f);
    return (int)q;
}

__device__ __forceinline__ unsigned int pack4(const float* v, float s) {
    unsigned int b0 = (unsigned int)quant_i(v[0], s) & 255u;
    unsigned int b1 = (unsigned int)quant_i(v[1], s) & 255u;
    unsigned int b2 = (unsigned int)quant_i(v[2], s) & 255u;
    unsigned int b3 = (unsigned int)quant_i(v[3], s) & 255u;
    return b0 | (b1 << 8) | (b2 << 16) | (b3 << 24);
}

// --- Phase 1: per-output-channel weight quant -> wT8[f][k] (int8), dscale[f] ---
// 64 blocks x 512 threads; block owns 8 f-cols (r3/r6/r10/r11/r12-verified).
__global__ __launch_bounds__(512)
void quant_w_kernel(const float* __restrict__ kern,
                    unsigned char* __restrict__ wT8,
                    float* __restrict__ dscale) {
    constexpr int TF = 8;
    constexpr int LDQ = K + 16;               // 528 B row stride (16B-aligned)
    __shared__ float pwmax[8][TF];
    __shared__ float wscl[TF];
    __shared__ unsigned char q_t[TF * LDQ];   // 8 x 528 int8

    const int t = threadIdx.x;
    const int lane = t & 63;
    const int wave = t >> 6;
    const int fl = t & 7;
    const int kc = t >> 3;          // 0..63
    const int f0 = blockIdx.x * TF;

    float v[8];
    const float* kp = kern + (size_t)(kc * 8) * F + f0 + fl;
    #pragma unroll
    for (int j = 0; j < 8; ++j) v[j] = kp[(size_t)j * F];

    float mx = 0.0f;
    #pragma unroll
    for (int j = 0; j < 8; ++j) mx = fmaxf(mx, fabsf(v[j]));
    #pragma unroll
    for (int d = 8; d < 64; d <<= 1) mx = fmaxf(mx, __shfl_xor(mx, d, 64));
    if (lane < 8) pwmax[wave][fl] = mx;
    __syncthreads();

    if (t < TF) {
        float m = 0.0f;
        #pragma unroll
        for (int w = 0; w < 8; ++w) m = fmaxf(m, pwmax[w][t]);
        m = fmaxf(m, 1e-7f);
        wscl[t] = 127.0f / m;
        dscale[f0 + t] = 3.0f * m / 16129.0f;   // 1/(a_scale*w_scale)
    }
    __syncthreads();

    const float ws = wscl[fl];
    {
        uint2 pk;
        pk.x = pack4(v + 0, ws);
        pk.y = pack4(v + 4, ws);
        *(uint2*)&q_t[fl * LDQ + kc * 8] = pk;
    }
    __syncthreads();

    if (t < 256) {
        const int r = t >> 5;
        const int c = t & 31;
        *(uint4*)&wT8[(size_t)(f0 + r) * K + c * 16] =
            *(const uint4*)&q_t[r * LDQ + c * 16];
    }
}

// --- Phase 2: FUSED quant-x + int8 MFMA GEMM, NO LDS / NO BARRIER ---
// 2048 blocks x 256 threads (4 waves). Each wave INDEPENDENTLY owns a
// 16-row x 256-col output tile: acc = 16 x i32x4 (64 regs). Per lane, the
// wave's ENTIRE A is 8 x int4v (gk=0..7): A[m16][quad*16+gk*64 ..+16] --
// quantized in-register from 4x float4 x-loads (16-row x 64B segments).
// gk+1's x-loads issue before gk's 16 MFMAs (latency hidden by dataflow, not
// barrier phases -- r6/r11/r12 all pinned at ~98us on barrier-phased
// schedules with all pipes <16% busy). B frags stream from L2-hot wT8.
// Paired waves (two col-halves of a strip) share the block -> x rows L1-hit.
// Operand bytes identical to the r10/r11/r12 absmax-verified path:
// A-frag = x[row][quad*16+gk*64..+16] int8; B-frag = wT8[col][same k]; C
// layout col=lane&15, row=quad*4+reg. Exact: ints, K-sum < 2^24.
__global__ __launch_bounds__(256, 4)
void gemm_kernel(const float* __restrict__ x,
                 const unsigned char* __restrict__ wT8,
                 const float* __restrict__ dscale,
                 const float* __restrict__ bias,
                 float* __restrict__ out) {
    const int t = threadIdx.x;
    const int lane = t & 63;
    const int wave = t >> 6;               // 0..3
    const int m16 = lane & 15;
    const int quad = lane >> 4;

    // XCD chunk swizzle (2048 % 8 == 0 -> bijective)
    const int g = blockIdx.x;
    const int logical = (g & 7) * 256 + (g >> 3);
    const int gwid = logical * 4 + wave;
    const int strip = gwid >> 1;           // 0..4095 -> rows strip*16
    const int half = gwid & 1;             // 0/1     -> cols half*256

    const float* xp = x + ((size_t)strip * 16 + m16) * K + quad * 16;
    const unsigned char* bp = wT8 + (size_t)(half * 256 + m16) * K + quad * 16;

    int4v acc[16];
    #pragma unroll
    for (int i = 0; i < 16; ++i) acc[i] = (int4v){0, 0, 0, 0};

    // prologue: x for gk=0
    float4 xf[4];
    #pragma unroll
    for (int j = 0; j < 4; ++j) xf[j] = *(const float4*)(xp + j * 4);

    #pragma unroll
    for (int gk = 0; gk < 8; ++gk) {
        // quantize the 16 f32 -> one int4v A-fragment (k-order, verified map)
        uint4 q;
        q.x = pack4((const float*)&xf[0], ASCALE);
        q.y = pack4((const float*)&xf[1], ASCALE);
        q.z = pack4((const float*)&xf[2], ASCALE);
        q.w = pack4((const float*)&xf[3], ASCALE);
        const int4v af = (int4v){(int)q.x, (int)q.y, (int)q.z, (int)q.w};

        // prefetch next gk's x (in flight across the 16 MFMAs below)
        if (gk < 7) {
            #pragma unroll
            for (int j = 0; j < 4; ++j)
                xf[j] = *(const float4*)(xp + (gk + 1) * 64 + j * 4);
        }

        #pragma unroll
        for (int nt = 0; nt < 16; ++nt) {
            const int4v bf = *(const int4v*)(bp + (size_t)nt * 16 * K + gk * 64);
            acc[nt] = __builtin_amdgcn_mfma_i32_16x16x64_i8(af, bf, acc[nt], 0, 0, 0);
        }
    }

    // epilogue: C layout col=lane&15, row=quad*4+reg (verified). Plain stores.
    const size_t orow0 = (size_t)strip * 16 + quad * 4;
    #pragma unroll
    for (int nt = 0; nt < 16; ++nt) {
        const int col = half * 256 + nt * 16 + m16;
        const float ds = dscale[col];
        const float bv = bias[col];
        #pragma unroll
        for (int r = 0; r < 4; ++r)
            out[(orow0 + r) * F + col] = (float)acc[nt][r] * ds + bv;
    }
}

extern "C" void kernel_launch(void* const* d_in, const int* in_sizes, int n_in,
                              void* d_out, int out_size, void* d_ws, size_t ws_size,
                              hipStream_t stream) {
    const float* x    = (const float*)d_in[0];
    const float* kern = (const float*)d_in[1];
    const float* bias = (const float*)d_in[2];
    float* out = (float*)d_out;

    unsigned char* wT8 = (unsigned char*)d_ws;                        // 256 KB
    float* dscale = (float*)((char*)d_ws + 256 * 1024);               // 2 KB

    quant_w_kernel<<<F / 8, 512, 0, stream>>>(kern, wT8, dscale);
    gemm_kernel<<<2048, 256, 0, stream>>>(x, wT8, dscale, bias, out);
}